// Round 1
// baseline (1302.153 us; speedup 1.0000x reference)
//
#include <hip/hip_runtime.h>
#include <hip/hip_bf16.h>

#define DEVI __device__ __forceinline__

DEVI float bf2f(unsigned short u){ return __uint_as_float(((unsigned int)u)<<16); }
DEVI unsigned short f2bf(float f){
  unsigned int u = __float_as_uint(f);
  unsigned int r = (u + 0x7fffu + ((u>>16)&1u)) >> 16;
  return (unsigned short)r;
}
DEVI float sigf(float x){ return 1.f/(1.f + __expf(-x)); }

// ---------------------------------------------------------------------------
// K1: fused conv front-end. One block per signal (B*S*C = 10240 signals).
// conv1(k7,s2,p3)+BN+ReLU+pool3 -> conv2(k5,s2,p2)+BN+ReLU+pool3 ->
// conv3(k3,s1,p1)+BN+ReLU -> mean(83) => feats[sig][64]
// LDS phases alias one 13796-float pool (~55KB): 2 blocks/CU.
// ---------------------------------------------------------------------------
__global__ __launch_bounds__(256) void k_conv(
    const float* __restrict__ x,
    const float* __restrict__ w1g, const float* __restrict__ c1b,
    const float* __restrict__ bg1, const float* __restrict__ bb1,
    const float* __restrict__ w2g, const float* __restrict__ c2b,
    const float* __restrict__ bg2, const float* __restrict__ bb2,
    const float* __restrict__ w3g, const float* __restrict__ c3b,
    const float* __restrict__ bg3, const float* __restrict__ bb3,
    float* __restrict__ feats)
{
  __shared__ float sm[13796];
  __shared__ float w1s[112];
  __shared__ float kb1[32], kb2[64], kb3[128];
  float* s1t = sm;            // [504][16], p = pos+2 (conv1 pooled out, pos 0..499)
  float* sx  = sm + 8064;     // 3012 floats, idx = t+4 (phase A)
  float* w2s = sm + 8064;     // phase B: [32][81] padded
  float* red = sm + 8064;     // phase C reduce [256]
  float* s2t = sm + 11076;    // [85][32], p = pos+1 (conv2 pooled out, pos 0..82)
  float* w3s = sm;            // phase C: [64][97] padded
  const int tid = threadIdx.x;
  const long sig = blockIdx.x;
  const float* xg = x + sig*3000;

  // stage x (float4) + pads + weights/consts
  {
    const float4* xg4 = reinterpret_cast<const float4*>(xg);
    float4* sx4 = reinterpret_cast<float4*>(sx+4);
    for (int i=tid; i<750; i+=256) sx4[i] = xg4[i];
    if (tid<4)  sx[tid]=0.f;
    if (tid<8)  sx[3004+tid]=0.f;
    if (tid<32) s1t[tid]=0.f;                  // pos=-2,-1 pad rows
    if (tid<112) w1s[tid]=w1g[tid];
    const float rs = rsqrtf(1.f+1e-5f);
    if (tid<16){ float s=bg1[tid]*rs; kb1[2*tid]=s; kb1[2*tid+1]=c1b[tid]*s+bb1[tid]; }
    if (tid<32){ float s=bg2[tid]*rs; kb2[2*tid]=s; kb2[2*tid+1]=c2b[tid]*s+bb2[tid]; }
    if (tid<64){ float s=bg3[tid]*rs; kb3[2*tid]=s; kb3[2*tid+1]=c3b[tid]*s+bb3[tid]; }
  }
  __syncthreads();

  // Phase A: conv1+bn+relu+pool -> s1t[pos+2][c], 16ch x 500
  for (int idx=tid; idx<8000; idx+=256){
    const int c = idx & 15, u = idx >> 4;
    const float* wc = w1s + c*7;
    float xv[11];
    #pragma unroll
    for (int r=0;r<11;r++) xv[r] = sx[6*u + r + 1];
    float a0=0.f,a1=0.f,a2=0.f;
    #pragma unroll
    for (int k=0;k<7;k++){ float w=wc[k]; a0 += xv[k]*w; a1 += xv[k+2]*w; a2 += xv[k+4]*w; }
    const float s=kb1[2*c], o=kb1[2*c+1];
    float y = fmaxf(fmaxf(a0*s+o, a1*s+o), a2*s+o);
    s1t[(u+2)*16 + c] = fmaxf(y, 0.f);
  }
  __syncthreads();

  for (int i=tid;i<2560;i+=256) w2s[(i/80)*81 + (i%80)] = w2g[i];
  if (tid<32){ s2t[tid]=0.f; s2t[84*32+tid]=0.f; }
  __syncthreads();

  // Phase B: conv2+bn+relu+pool -> s2t[pos+1][oc], 32ch x 83
  {
    const int oc = tid & 31, ug = tid >> 5;
    float wreg[80];
    #pragma unroll
    for (int i=0;i<80;i++) wreg[i] = w2s[oc*81+i];   // stride 81: conflict-free
    const float s=kb2[2*oc], o=kb2[2*oc+1];
    for (int u=ug; u<83; u+=8){
      float acc0=0.f, acc1=0.f, acc2=0.f;
      #pragma unroll
      for (int rp=0; rp<9; ++rp){
        const float4* row = reinterpret_cast<const float4*>(s1t + (6*u+rp)*16);
        float4 v0=row[0], v1=row[1], v2=row[2], v3=row[3];
        float v[16] = {v0.x,v0.y,v0.z,v0.w, v1.x,v1.y,v1.z,v1.w,
                       v2.x,v2.y,v2.z,v2.w, v3.x,v3.y,v3.z,v3.w};
        #pragma unroll
        for (int tp=0; tp<3; ++tp){
          const int k = rp - 2*tp;
          if (k>=0 && k<5){
            float ssum = 0.f;
            #pragma unroll
            for (int ic=0; ic<16; ++ic) ssum += v[ic]*wreg[ic*5+k];
            if (tp==0) acc0 += ssum; else if (tp==1) acc1 += ssum; else acc2 += ssum;
          }
        }
      }
      float y = fmaxf(fmaxf(acc0*s+o, acc1*s+o), acc2*s+o);
      s2t[(u+1)*32 + oc] = fmaxf(y, 0.f);
    }
  }
  __syncthreads();
  for (int i=tid;i<6144;i+=256) w3s[(i/96)*97 + (i%96)] = w3g[i];
  __syncthreads();

  // Phase C: conv3+bn+relu+mean -> feats[sig][64]
  {
    const int oc = tid & 63;
    float w3r[96];
    #pragma unroll
    for (int i=0;i<96;i++) w3r[i] = w3s[oc*97+i];    // stride 97: conflict-free
    const float s=kb3[2*oc], o=kb3[2*oc+1];
    float acc = 0.f;
    for (int t=(tid>>6); t<83; t+=4){
      float cs = 0.f;
      #pragma unroll
      for (int k=0;k<3;k++){
        const float4* row = reinterpret_cast<const float4*>(s2t + (t+k)*32);
        #pragma unroll
        for (int q=0;q<8;q++){
          float4 v = row[q];
          cs += v.x*w3r[(4*q+0)*3+k] + v.y*w3r[(4*q+1)*3+k]
              + v.z*w3r[(4*q+2)*3+k] + v.w*w3r[(4*q+3)*3+k];
        }
      }
      acc += fmaxf(cs*s+o, 0.f);
    }
    red[tid] = acc;
  }
  __syncthreads();
  if (tid<64){
    float r = red[tid]+red[tid+64]+red[tid+128]+red[tid+192];
    feats[sig*64 + tid] = r * (1.f/83.f);
  }
}

// ---------------------------------------------------------------------------
// K2: build normalized adjacency An (8x8) from edge_index (2,56)
// ---------------------------------------------------------------------------
__global__ void k_an(const int* __restrict__ ei, float* __restrict__ an){
  __shared__ float A[64];
  __shared__ float dinv[8];
  const int tid = threadIdx.x;
  if (tid<64) A[tid] = ((tid>>3)==(tid&7)) ? 1.f : 0.f;
  __syncthreads();
  if (tid==0){
    for (int e=0;e<56;e++){ int s=ei[e], d=ei[56+e]; A[d*8+s] += 1.f; }
  }
  __syncthreads();
  if (tid<8){ float s=0.f; for (int j=0;j<8;j++) s+=A[tid*8+j]; dinv[tid]=rsqrtf(s); }
  __syncthreads();
  if (tid<64) an[tid] = A[tid]*dinv[tid>>3]*dinv[tid&7];
}

// ---------------------------------------------------------------------------
// Generic f32 GEMM: C[M,N] = X[M,K] @ W[N,K]^T (+b1 +b2). Tile 128x64, BK=8.
// M%128==0, N%64==0, K%8==0.
// ---------------------------------------------------------------------------
__global__ __launch_bounds__(256) void k_gemm_nt(
  const float* __restrict__ X, const float* __restrict__ W,
  const float* __restrict__ b1, const float* __restrict__ b2,
  float* __restrict__ C, int M, int N, int K)
{
  __shared__ float Xs[8][132];
  __shared__ float Ws[8][68];
  const int tid = threadIdx.x;
  const int m0 = blockIdx.y*128, n0 = blockIdx.x*64;
  const int tm = tid >> 4, tn = tid & 15;
  float acc[8][4] = {};
  const int xr = tid >> 1,          xk = (tid & 1)*4;
  const int wr = (tid & 127) >> 1,  wk = (tid & 1)*4;

  for (int k0=0; k0<K; k0+=8){
    float4 xa = *reinterpret_cast<const float4*>(X + (long)(m0+xr)*K + k0 + xk);
    float4 wa = make_float4(0,0,0,0);
    if (tid<128) wa = *reinterpret_cast<const float4*>(W + (long)(n0+wr)*K + k0 + wk);
    __syncthreads();
    Xs[xk+0][xr]=xa.x; Xs[xk+1][xr]=xa.y; Xs[xk+2][xr]=xa.z; Xs[xk+3][xr]=xa.w;
    if (tid<128){ Ws[wk+0][wr]=wa.x; Ws[wk+1][wr]=wa.y; Ws[wk+2][wr]=wa.z; Ws[wk+3][wr]=wa.w; }
    __syncthreads();
    #pragma unroll
    for (int kk=0;kk<8;kk++){
      float4 a0 = *reinterpret_cast<const float4*>(&Xs[kk][tm*8]);
      float4 a1 = *reinterpret_cast<const float4*>(&Xs[kk][tm*8+4]);
      float4 b  = *reinterpret_cast<const float4*>(&Ws[kk][tn*4]);
      float av[8] = {a0.x,a0.y,a0.z,a0.w,a1.x,a1.y,a1.z,a1.w};
      float bv[4] = {b.x,b.y,b.z,b.w};
      #pragma unroll
      for (int i=0;i<8;i++)
        #pragma unroll
        for (int j=0;j<4;j++) acc[i][j] += av[i]*bv[j];
    }
  }
  float bias[4] = {0.f,0.f,0.f,0.f};
  if (b1){ float4 t = *reinterpret_cast<const float4*>(b1 + n0 + tn*4);
           bias[0]+=t.x; bias[1]+=t.y; bias[2]+=t.z; bias[3]+=t.w; }
  if (b2){ float4 t = *reinterpret_cast<const float4*>(b2 + n0 + tn*4);
           bias[0]+=t.x; bias[1]+=t.y; bias[2]+=t.z; bias[3]+=t.w; }
  #pragma unroll
  for (int i=0;i<8;i++){
    const long m = m0 + tm*8 + i;
    float4 o;
    o.x = acc[i][0]+bias[0]; o.y = acc[i][1]+bias[1];
    o.z = acc[i][2]+bias[2]; o.w = acc[i][3]+bias[3];
    *reinterpret_cast<float4*>(C + m*N + n0 + tn*4) = o;
  }
}

// ---------------------------------------------------------------------------
// K4: g1[g][i][j] = relu( sum_c An[i][c]*tmp0[g][c][j] + b0[j] )
// ---------------------------------------------------------------------------
__global__ __launch_bounds__(256) void k_mix1(
  const float* __restrict__ tmp0, const float* __restrict__ An,
  const float* __restrict__ b0, float* __restrict__ g1)
{
  __shared__ float ans[64];
  if (threadIdx.x < 64) ans[threadIdx.x] = An[threadIdx.x];
  __syncthreads();
  const long idx = (long)blockIdx.x*256 + threadIdx.x;   // over 1280*128
  const int g = (int)(idx >> 7), j = (int)(idx & 127);
  const float* base = tmp0 + (long)g*1024;
  float t[8];
  #pragma unroll
  for (int c=0;c<8;c++) t[c] = base[c*128+j];
  const float bj = b0[j];
  #pragma unroll
  for (int i=0;i<8;i++){
    float s = bj;
    #pragma unroll
    for (int c=0;c<8;c++) s += ans[i*8+c]*t[c];
    g1[(long)g*1024 + i*128 + j] = fmaxf(s, 0.f);
  }
}

// ---------------------------------------------------------------------------
// K6: g2 = An@tmp1 + b1 ; LN over j (128) per row ; mean over 8 nodes -> emb
// ---------------------------------------------------------------------------
__global__ __launch_bounds__(128) void k_mix2(
  const float* __restrict__ tmp1, const float* __restrict__ An,
  const float* __restrict__ b1, const float* __restrict__ lng,
  const float* __restrict__ lnb, float* __restrict__ emb)
{
  const int g = blockIdx.x, j = threadIdx.x;
  __shared__ float ans[64];
  __shared__ float g2s[8*128];
  __shared__ float stats[16];
  if (j<64) ans[j] = An[j];
  const float* base = tmp1 + (long)g*1024;
  float t[8];
  #pragma unroll
  for (int c=0;c<8;c++) t[c] = base[c*128 + j];
  const float bj = b1[j];
  __syncthreads();
  #pragma unroll
  for (int i=0;i<8;i++){
    float s = bj;
    #pragma unroll
    for (int c=0;c<8;c++) s += ans[i*8+c]*t[c];
    g2s[i*128+j] = s;
  }
  __syncthreads();
  {
    const int c = j>>4, l = j&15;
    float s=0.f, sq=0.f;
    for (int jj=l; jj<128; jj+=16){ float v=g2s[c*128+jj]; s+=v; sq+=v*v; }
    #pragma unroll
    for (int off=8; off>=1; off>>=1){ s += __shfl_xor(s, off); sq += __shfl_xor(sq, off); }
    if (l==0){
      float m = s*(1.f/128.f);
      stats[2*c] = m;
      stats[2*c+1] = rsqrtf(sq*(1.f/128.f) - m*m + 1e-5f);
    }
  }
  __syncthreads();
  float acc=0.f;
  #pragma unroll
  for (int i=0;i<8;i++) acc += (g2s[i*128+j] - stats[2*i]) * stats[2*i+1];
  emb[(long)g*128 + j] = lng[j]*acc*0.125f + lnb[j];
}

// ---------------------------------------------------------------------------
// K7b: transpose w_hh (1024,256) f32 -> wt (256,1024) bf16
// ---------------------------------------------------------------------------
__global__ __launch_bounds__(256) void k_tr(
  const float* __restrict__ in, unsigned short* __restrict__ out)
{
  const int i = blockIdx.x*256 + threadIdx.x;   // 262144
  const int g = i & 1023, j = i >> 10;
  out[i] = f2bf(in[g*256 + j]);
}

// ---------------------------------------------------------------------------
// K8: one LSTM layer, both directions. Block = (batch, dir). h,c block-local.
// Thread accumulates 4 consecutive gate rows (grow..grow+3) via bf16 ushort4
// weight stream; then owns hidden unit `tid` for the c/h update.
// ---------------------------------------------------------------------------
__global__ __launch_bounds__(256) void k_lstm(
    const float* __restrict__ xsf, const float* __restrict__ xsr,
    const unsigned short* __restrict__ wtf, const unsigned short* __restrict__ wtr,
    float* __restrict__ out)
{
  const int S = 20;
  const int b = blockIdx.x >> 1, dir = blockIdx.x & 1;
  const float* xs = dir ? xsr : xsf;
  const unsigned short* wt = dir ? wtr : wtf;
  __shared__ float hs[256];
  __shared__ float gs[1024];
  const int tid = threadIdx.x;
  const int grow = (tid>>6)*256 + (tid&63)*4;
  hs[tid] = 0.f;
  float cc = 0.f;
  __syncthreads();
  for (int st=0; st<S; ++st){
    const int t = dir ? (S-1-st) : st;
    const float* xrow = xs + ((long)b*S + t)*1024;
    float4 a = *reinterpret_cast<const float4*>(xrow + grow);
    float acc0=a.x, acc1=a.y, acc2=a.z, acc3=a.w;
    #pragma unroll 4
    for (int j=0;j<256;++j){
      const float hv = hs[j];
      ushort4 w = *reinterpret_cast<const ushort4*>(wt + (long)j*1024 + grow);
      acc0 += hv*bf2f(w.x);
      acc1 += hv*bf2f(w.y);
      acc2 += hv*bf2f(w.z);
      acc3 += hv*bf2f(w.w);
    }
    gs[grow+0]=acc0; gs[grow+1]=acc1; gs[grow+2]=acc2; gs[grow+3]=acc3;
    __syncthreads();
    const float gi = gs[tid], gf = gs[256+tid], gg = gs[512+tid], go = gs[768+tid];
    cc = sigf(gf)*cc + sigf(gi)*tanhf(gg);
    const float h = sigf(go)*tanhf(cc);
    hs[tid] = h;
    out[((long)b*S + t)*512 + dir*256 + tid] = h;
    __syncthreads();
  }
}

// ---------------------------------------------------------------------------
// K11: final LayerNorm(512) + classifier (5) per row
// ---------------------------------------------------------------------------
__global__ __launch_bounds__(128) void k_lncls(
  const float* __restrict__ in, const float* __restrict__ g,
  const float* __restrict__ b, const float* __restrict__ cw,
  const float* __restrict__ cb, float* __restrict__ out)
{
  const int row = blockIdx.x, tid = threadIdx.x;
  __shared__ float sred[4];
  __shared__ float cred[2][5];
  float4 v = *reinterpret_cast<const float4*>(in + (long)row*512 + tid*4);
  float s  = v.x+v.y+v.z+v.w;
  float sq = v.x*v.x+v.y*v.y+v.z*v.z+v.w*v.w;
  #pragma unroll
  for (int off=32; off>=1; off>>=1){ s += __shfl_xor(s, off); sq += __shfl_xor(sq, off); }
  const int wv = tid>>6;
  if ((tid&63)==0){ sred[wv*2]=s; sred[wv*2+1]=sq; }
  __syncthreads();
  const float S = sred[0]+sred[2], SQ = sred[1]+sred[3];
  const float m = S*(1.f/512.f);
  const float rstd = rsqrtf(SQ*(1.f/512.f) - m*m + 1e-5f);
  float4 gg = *reinterpret_cast<const float4*>(g + tid*4);
  float4 bb = *reinterpret_cast<const float4*>(b + tid*4);
  const float n0 = (v.x-m)*rstd*gg.x + bb.x;
  const float n1 = (v.y-m)*rstd*gg.y + bb.y;
  const float n2 = (v.z-m)*rstd*gg.z + bb.z;
  const float n3 = (v.w-m)*rstd*gg.w + bb.w;
  #pragma unroll
  for (int nc=0; nc<5; ++nc){
    float4 w = *reinterpret_cast<const float4*>(cw + nc*512 + tid*4);
    float p = n0*w.x + n1*w.y + n2*w.z + n3*w.w;
    #pragma unroll
    for (int off=32; off>=1; off>>=1) p += __shfl_xor(p, off);
    if ((tid&63)==0) cred[wv][nc] = p;
  }
  __syncthreads();
  if (tid < 5) out[(long)row*5 + tid] = cred[0][tid] + cred[1][tid] + cb[tid];
}

// ---------------------------------------------------------------------------
extern "C" void kernel_launch(void* const* d_in, const int* in_sizes, int n_in,
                              void* d_out, int out_size, void* d_ws, size_t ws_size,
                              hipStream_t stream)
{
  const float* x     = (const float*)d_in[0];
  const int*   ei    = (const int*)d_in[1];
  const float* w1    = (const float*)d_in[2];
  const float* c1b   = (const float*)d_in[3];
  const float* bg1   = (const float*)d_in[4];
  const float* bb1   = (const float*)d_in[5];
  const float* w2    = (const float*)d_in[6];
  const float* c2b   = (const float*)d_in[7];
  const float* bg2   = (const float*)d_in[8];
  const float* bb2   = (const float*)d_in[9];
  const float* w3    = (const float*)d_in[10];
  const float* c3b   = (const float*)d_in[11];
  const float* bg3   = (const float*)d_in[12];
  const float* bb3   = (const float*)d_in[13];
  const float* gcn0w = (const float*)d_in[14];
  const float* gcn0b = (const float*)d_in[15];
  const float* gcn1w = (const float*)d_in[16];
  const float* gcn1b = (const float*)d_in[17];
  const float* lng   = (const float*)d_in[18];
  const float* lnb   = (const float*)d_in[19];
  const float* wih0  = (const float*)d_in[20];
  const float* whh0  = (const float*)d_in[21];
  const float* bih0  = (const float*)d_in[22];
  const float* bhh0  = (const float*)d_in[23];
  const float* wih0r = (const float*)d_in[24];
  const float* whh0r = (const float*)d_in[25];
  const float* bih0r = (const float*)d_in[26];
  const float* bhh0r = (const float*)d_in[27];
  const float* wih1  = (const float*)d_in[28];
  const float* whh1  = (const float*)d_in[29];
  const float* bih1  = (const float*)d_in[30];
  const float* bhh1  = (const float*)d_in[31];
  const float* wih1r = (const float*)d_in[32];
  const float* whh1r = (const float*)d_in[33];
  const float* bih1r = (const float*)d_in[34];
  const float* bhh1r = (const float*)d_in[35];
  const float* lstmg = (const float*)d_in[36];
  const float* lstmb = (const float*)d_in[37];
  const float* clsw  = (const float*)d_in[38];
  const float* clsb  = (const float*)d_in[39];
  float* ws  = (float*)d_ws;
  float* out = (float*)d_out;

  // workspace layout (floats); total 7,897,344 floats = 31.6 MB
  float* An    = ws + 0;
  float* feats = ws + 256;
  float* tmp   = ws + 655616;    // tmp0 and tmp1 (aliased)
  float* g1b   = ws + 1966336;
  float* emb   = ws + 3277056;
  float* xsf   = ws + 3440896;   // reused for layer1
  float* xsr   = ws + 4751616;
  float* l0    = ws + 6062336;
  float* l1    = ws + 6717696;
  unsigned short* wt0f = (unsigned short*)(ws + 7373056);
  unsigned short* wt0r = (unsigned short*)(ws + 7504128);
  unsigned short* wt1f = (unsigned short*)(ws + 7635200);
  unsigned short* wt1r = (unsigned short*)(ws + 7766272);

  // Stage 1: conv front-end
  k_conv<<<10240, 256, 0, stream>>>(x, w1,c1b,bg1,bb1, w2,c2b,bg2,bb2,
                                    w3,c3b,bg3,bb3, feats);
  // Adjacency + weight transposes (independent of k_conv output)
  k_an<<<1, 64, 0, stream>>>(ei, An);
  k_tr<<<1024,256,0,stream>>>(whh0,  wt0f);
  k_tr<<<1024,256,0,stream>>>(whh0r, wt0r);
  k_tr<<<1024,256,0,stream>>>(whh1,  wt1f);
  k_tr<<<1024,256,0,stream>>>(whh1r, wt1r);

  // Stage 2: GCN
  k_gemm_nt<<<dim3(2, 80), 256, 0, stream>>>(feats, gcn0w, nullptr, nullptr, tmp, 10240, 128, 64);
  k_mix1<<<640,256,0,stream>>>(tmp, An, gcn0b, g1b);
  k_gemm_nt<<<dim3(2, 80), 256, 0, stream>>>(g1b, gcn1w, nullptr, nullptr, tmp, 10240, 128, 128);
  k_mix2<<<1280,128,0,stream>>>(tmp, An, gcn1b, lng, lnb, emb);

  // Stage 3: BiLSTM layer 0
  k_gemm_nt<<<dim3(16, 10), 256, 0, stream>>>(emb, wih0,  bih0,  bhh0,  xsf, 1280, 1024, 128);
  k_gemm_nt<<<dim3(16, 10), 256, 0, stream>>>(emb, wih0r, bih0r, bhh0r, xsr, 1280, 1024, 128);
  k_lstm<<<128, 256, 0, stream>>>(xsf, xsr, wt0f, wt0r, l0);

  // BiLSTM layer 1
  k_gemm_nt<<<dim3(16, 10), 256, 0, stream>>>(l0, wih1,  bih1,  bhh1,  xsf, 1280, 1024, 512);
  k_gemm_nt<<<dim3(16, 10), 256, 0, stream>>>(l0, wih1r, bih1r, bhh1r, xsr, 1280, 1024, 512);
  k_lstm<<<128, 256, 0, stream>>>(xsf, xsr, wt1f, wt1r, l1);

  // Stage 4: LN + classifier
  k_lncls<<<1280, 128, 0, stream>>>(l1, lstmg, lstmb, clsw, clsb, out);
}